// Round 5
// baseline (1310.181 us; speedup 1.0000x reference)
//
#include <hip/hip_runtime.h>
#include <math.h>

#define B_DIM 128
#define T_DIM 50
#define LEAF  4880
#define A_DIM 64
#define ATTN  128
#define RNN   128
#define NC    283
#define M_TOT (B_DIM*T_DIM)   // 6400
#define KSPLIT 10
#define NCH 153               // ceil(4880/32); chunk 152 has 16 valid k
#define WT_PLANE (NCH*512*8)  // 626688 ushort per plane (hi / lo)

using short8 = __attribute__((ext_vector_type(8))) short;
using f32x4  = __attribute__((ext_vector_type(4))) float;

__device__ __forceinline__ float sigmoidf_(float x) {
  return 1.0f / (1.0f + __expf(-x));
}

// RNE fp32 -> bf16 bits
__device__ __forceinline__ unsigned short f32_to_bf16_rne(float f) {
  unsigned int u = __float_as_uint(f);
  unsigned int r = u + 0x7FFFu + ((u >> 16) & 1u);
  return (unsigned short)(r >> 16);
}
__device__ __forceinline__ float bf16_bits_to_f32(unsigned short b) {
  return __uint_as_float(((unsigned int)b) << 16);
}

// ---------------------------------------------------------------------------
// Pre-transpose W[4880,128] into MFMA B-fragment order, hi/lo bf16 planes.
// ---------------------------------------------------------------------------
__global__ __launch_bounds__(256) void k_prep_wt(
    const float* __restrict__ Wd, unsigned short* __restrict__ Wt) {
  const int u = blockIdx.x * 256 + threadIdx.x;   // 0 .. 78335 (NCH*512)
  const int c = u >> 9, rem = u & 511;
  const int nt = rem >> 6, lane = rem & 63;
  const int n = nt * 16 + (lane & 15);
  const int kb = c * 32 + ((lane >> 4) << 3);
  short8 h8, l8;
  #pragma unroll
  for (int j = 0; j < 8; ++j) {
    int k = kb + j;
    float v = (k < LEAF) ? Wd[(size_t)k * 128 + n] : 0.0f;
    unsigned short hb = f32_to_bf16_rne(v);
    unsigned short lb = f32_to_bf16_rne(v - bf16_bits_to_f32(hb));
    h8[j] = (short)hb;
    l8[j] = (short)lb;
  }
  *(short8*)&Wt[(size_t)u * 8] = h8;
  *(short8*)&Wt[(size_t)WT_PLANE + (size_t)u * 8] = l8;
}

// ---------------------------------------------------------------------------
// Big GEMM via MFMA, v7: BM=128, KSPLIT=10.
// R10 post-mortem: BM=32->64 landed on-model (-18us total): latency model
// time ~ total-wave-chunks x per-wave-chunk-serial-latency / 1024 SIMDs
// confirmed. v7 halves wave-chunks again (61,200), latency/chunk grows ~1.4x
// (8 msubs, 24 MFMA, 16 ds_read) -> predict ~45us. KSPLIT=10 keeps grid=500
// (2 blocks/CU at 32KB LDS dbuf). A staging: 4 threads/row x 8 floats
// (2 dwordx4/thread) -> vmcnt entry set = [B(c)x2, A(c+1)x2], waits 4/2/0.
// Arithmetic identical (3-MFMA hi/lo) -> absmax bit-identical.
// ---------------------------------------------------------------------------
__global__ __launch_bounds__(512, 4) void k_gemm_mfma(
    const float* __restrict__ Ax, const unsigned short* __restrict__ Wt,
    float* __restrict__ P) {
  __shared__ __align__(16) unsigned short As[2][8192];  // 32 KB [buf][plane*4096 + frag]
  const int tid  = threadIdx.x;
  const int lane = tid & 63;
  const int w    = tid >> 6;     // wave id = nt tile (16 cols each)
  const int M0   = blockIdx.x * 128;
  const int s    = blockIdx.y;
  const int c0   = (s * NCH) / KSPLIT;
  const int c1   = ((s + 1) * NCH) / KSPLIT;

  // A staging map: row am = tid>>2 (0..127), k-octet kq = tid&3.
  // 4 threads cover one row's 32 floats (128B contiguous, coalesced).
  const int am = tid >> 2;
  const int kq = tid & 3;
  const float* pA = Ax + (size_t)(M0 + am) * LEAF;
  // ushort index (within plane) matching the MFMA A-fragment read layout:
  // elem A[row][k] lives at (row>>4)*512 + ((row&15) + 16*(k>>3))*8 + (k&7)
  const int a_idx = (am >> 4) * 512 + ((am & 15) + 16 * kq) * 8;

  f32x4 acc[8];
  #pragma unroll
  for (int i = 0; i < 8; ++i) {
    #pragma unroll
    for (int q = 0; q < 4; ++q) acc[i][q] = 0.0f;
  }

  float4 rA_a0, rA_a1, rA_b0, rA_b1;   // ping-pong A prefetch (depth 2, 8 floats each)
  short8 bh_a, bl_a, bh_b, bl_b;       // ping-pong B fragments (depth 1)

  auto issueB = [&](int c, short8& bh, short8& bl) {
    const size_t o = ((size_t)c * 512 + w * 64 + lane) * 8;
    bh = *(const short8*)&Wt[o];
    bl = *(const short8*)&Wt[(size_t)WT_PLANE + o];
  };
  auto issueA = [&](int c, float4& r0, float4& r1) {
    int kk = c * 32 + kq * 8;
    kk = min(kk, LEAF - 8);            // clamp (no skip): uniform vmcnt counts;
    r0 = *(const float4*)(pA + kk);    // clamped dup data x Wt zero rows = 0
    r1 = *(const float4*)(pA + kk + 4);
  };
  auto storeA = [&](int p, float4 r0, float4 r1) {
    float v[8] = {r0.x, r0.y, r0.z, r0.w, r1.x, r1.y, r1.z, r1.w};
    short8 h8, l8;
    #pragma unroll
    for (int j = 0; j < 8; ++j) {
      unsigned short hb = f32_to_bf16_rne(v[j]);
      unsigned short lb = f32_to_bf16_rne(v[j] - bf16_bits_to_f32(hb));
      h8[j] = (short)hb;
      l8[j] = (short)lb;
    }
    *(short8*)&As[p][a_idx] = h8;
    *(short8*)&As[p][4096 + a_idx] = l8;
  };
  auto compute = [&](int p, const short8& bh, const short8& bl) {
    #pragma unroll
    for (int m = 0; m < 8; ++m) {
      short8 a_hi = *(const short8*)&As[p][m * 512 + lane * 8];
      short8 a_lo = *(const short8*)&As[p][4096 + m * 512 + lane * 8];
      acc[m] = __builtin_amdgcn_mfma_f32_16x16x32_bf16(a_hi, bl, acc[m], 0, 0, 0);
      acc[m] = __builtin_amdgcn_mfma_f32_16x16x32_bf16(a_lo, bh, acc[m], 0, 0, 0);
      acc[m] = __builtin_amdgcn_mfma_f32_16x16x32_bf16(a_hi, bh, acc[m], 0, 0, 0);
    }
  };

  // ---- prologue ----
  {
    float4 t0, t1;
    issueA(c0, t0, t1);
    asm volatile("s_waitcnt vmcnt(0)" ::: "memory");
    storeA(0, t0, t1);
    issueB(c0, bh_a, bl_a);                          // 2 loads
    asm volatile("" ::: "memory");
    if (c0 + 1 < c1) issueA(c0 + 1, rA_a0, rA_a1);   // 2 loads
    asm volatile("s_waitcnt lgkmcnt(0)" ::: "memory");
    __builtin_amdgcn_s_barrier();
    asm volatile("" ::: "memory");
    // outstanding entering loop: [B(c0) x2, A(c0+1) x2]
  }

  // Per iter: outstanding on entry = [B(c)x2, A(c+1)x2] (from prev iter).
  // Issue B(c+1)x2, A(c+2)x2; counted wait drains exactly the entry set;
  // compute with B(c); storeA(A(c+1)); lgkm; barrier.
#define GEMM_ITER(BHc, BLc, BHn, BLn, RAc0, RAc1, RAn0, RAn1)                 \
  {                                                                           \
    const int p = (c - c0) & 1;                                               \
    const bool has1 = (c + 1 < c1), has2 = (c + 2 < c1);                      \
    if (has1) { issueB(c + 1, BHn, BLn); asm volatile("" ::: "memory"); }     \
    if (has2) { issueA(c + 2, RAn0, RAn1); asm volatile("" ::: "memory"); }   \
    if (has1) {                                                               \
      if (has2) { asm volatile("s_waitcnt vmcnt(4)" ::: "memory"); }          \
      else      { asm volatile("s_waitcnt vmcnt(2)" ::: "memory"); }          \
    } else      { asm volatile("s_waitcnt vmcnt(0)" ::: "memory"); }          \
    compute(p, BHc, BLc);                                                     \
    if (has1) storeA(p ^ 1, RAc0, RAc1);                                      \
    asm volatile("s_waitcnt lgkmcnt(0)" ::: "memory");                        \
    __builtin_amdgcn_s_barrier();                                             \
    asm volatile("" ::: "memory");                                            \
    ++c;                                                                      \
  }

  int c = c0;
  while (c < c1) {
    GEMM_ITER(bh_a, bl_a, bh_b, bl_b, rA_a0, rA_a1, rA_b0, rA_b1);
    if (c < c1) GEMM_ITER(bh_b, bl_b, bh_a, bl_a, rA_b0, rA_b1, rA_a0, rA_a1);
  }
#undef GEMM_ITER

  // epilogue: C/D layout col=lane&15, row=(lane>>4)*4+r ; cols = w*16..w*16+15
  float* outp = P + (size_t)s * ((size_t)M_TOT * 128);
  const int col0 = w * 16 + (lane & 15);
  #pragma unroll
  for (int m = 0; m < 8; ++m) {
    const int rbase = M0 + m * 16 + ((lane >> 4) << 2);
    #pragma unroll
    for (int r = 0; r < 4; ++r)
      outp[(size_t)(rbase + r) * 128 + col0] = acc[m][r];
  }
}

// ---------------------------------------------------------------------------
// Reduce KSPLIT partials + tanh (X aliases P slot 0; elementwise-safe).
// ---------------------------------------------------------------------------
__global__ __launch_bounds__(256) void k_reduce_tanh(
    float* __restrict__ P, float* __restrict__ X) {
  const size_t i = ((size_t)blockIdx.x * 256 + threadIdx.x) * 4;
  float4 a = *(const float4*)&P[i];
  #pragma unroll
  for (int s = 1; s < KSPLIT; ++s) {
    float4 b = *(const float4*)&P[(size_t)s * (M_TOT * 128) + i];
    a.x += b.x; a.y += b.y; a.z += b.z; a.w += b.w;
  }
  a.x = tanhf(a.x); a.y = tanhf(a.y); a.z = tanhf(a.z); a.w = tanhf(a.w);
  *(float4*)&X[i] = a;
}

// ---------------------------------------------------------------------------
// Generic small GEMM: C[M,N] = A[M,K] @ Bw[N,K]^T + bias  (opt sigmoid*mask)
// ---------------------------------------------------------------------------
template<int K, int ACT>
__global__ __launch_bounds__(256) void k_gemm_bn(
    const float* __restrict__ A, const float* __restrict__ Bw,
    const float* __restrict__ bias, const float* __restrict__ maskv,
    float* __restrict__ C, int N, int ldc) {
  __shared__ __align__(16) float Asm[32][K + 4];
  const int tid = threadIdx.x;
  const int m0 = blockIdx.x * 32;
  const int n0 = blockIdx.y * 64;
  constexpr int K4 = K / 4;

  #pragma unroll
  for (int i = 0; i < (32 * K4) / 256; ++i) {
    int idx = tid + i * 256;
    int row = idx / K4, k4 = idx % K4;
    float4 v = *(const float4*)&A[(size_t)(m0 + row) * K + k4 * 4];
    *(float4*)&Asm[row][k4 * 4] = v;
  }
  __syncthreads();

  const int n2 = tid & 31, mg = tid >> 5;
  const int n = n0 + n2 * 2;
  const int ns0 = min(n, N - 1), ns1 = min(n + 1, N - 1);
  const float* Bp0 = Bw + (size_t)ns0 * K;
  const float* Bp1 = Bw + (size_t)ns1 * K;

  float acc[4][2] = {};
  #pragma unroll 4
  for (int k = 0; k < K; k += 4) {
    float4 b0 = *(const float4*)&Bp0[k];
    float4 b1 = *(const float4*)&Bp1[k];
    #pragma unroll
    for (int r = 0; r < 4; ++r) {
      float4 a = *(const float4*)&Asm[mg * 4 + r][k];
      acc[r][0] += a.x * b0.x + a.y * b0.y + a.z * b0.z + a.w * b0.w;
      acc[r][1] += a.x * b1.x + a.y * b1.y + a.z * b1.z + a.w * b1.w;
    }
  }

  #pragma unroll
  for (int r = 0; r < 4; ++r) {
    int m = m0 + mg * 4 + r;
    #pragma unroll
    for (int c = 0; c < 2; ++c) {
      int nn = n + c;
      if (nn < N) {
        float v = acc[r][c] + bias[nn];
        if (ACT) v = sigmoidf_(v) * maskv[m];
        C[(size_t)m * ldc + nn] = v;
      }
    }
  }
}

// ---------------------------------------------------------------------------
// Fused 2-layer GRU scan (v4). One block per batch row; 1024 threads.
// R10 insight: layer2 at step t needs only h1[t] -> run layer2 ONE STEP
// LAGGED in the same block. Threads 0-511 (role 0) = layer1 (proven k_gru
// inner loop, xW0 precomputed by k_gemm_bn). Threads 512-1023 (role 1) =
// layer2: BOTH Whh1@h2[t-2] and Wih1@h1[t-1] as in-register matvecs (the
// xW1 GEMM is absorbed -- k_gemm_bn#2 and the H1 round-trip eliminated).
// ONE barrier per step (vs 4 across the old 3-kernel chain), 51 iters.
// hs1/hs2 double-buffered: at iter t, l1 reads hs1[cur] (h1[t-1]) writes
// hs1[cur^1]; l2 reads hs1[cur] (h1[t-1]) + hs2[cur] (h2[t-2]), writes
// hs2[cur^1] (h2[t-1]) + Hout[t-1]. Init: all hs buffers zero.
// Weights per l2 thread: Whh1 96 + Wih1 96 VGPR (wave-uniform role split;
// register arrays indexed by unroll constants only -- R4 lesson).
// Gate math identical to proven k_gru (n-bias INSIDE r*).
// ---------------------------------------------------------------------------
__global__ __launch_bounds__(1024) void k_gru2(
    const float* __restrict__ xW,
    const float* __restrict__ Whh0, const float* __restrict__ bhh0,
    const float* __restrict__ Wih1, const float* __restrict__ bih1,
    const float* __restrict__ Whh1, const float* __restrict__ bhh1,
    float* __restrict__ Hout) {
  const int b    = blockIdx.x;
  const int tid  = threadIdx.x;
  const int role = tid >> 9;          // 0 = layer1, 1 = layer2 (lagged)
  const int t5   = tid & 511;
  const int j    = t5 >> 2;
  const int qf   = t5 & 3;
  __shared__ __align__(16) float hs1[2][128];
  __shared__ __align__(16) float hs2[2][128];

  float4 wr[8], wz[8], wn[8];   // W_hh of my layer (rotation folded into load)
  float4 ur[8], uz[8], un[8];   // role 1: W_ih1 (role 0: dummy-loaded, unused)
  {
    const float* Whh = role ? Whh1 : Whh0;
    const float* pr = Whh + (size_t)j * 128 + qf * 32;
    const float* pz = Whh + (size_t)(j + 128) * 128 + qf * 32;
    const float* pn = Whh + (size_t)(j + 256) * 128 + qf * 32;
    const float* U  = role ? Wih1 : Whh0;   // valid dummy base for role 0
    const float* qr = U + (size_t)j * 128 + qf * 32;
    const float* qz = U + (size_t)(j + 128) * 128 + qf * 32;
    const float* qn = U + (size_t)(j + 256) * 128 + qf * 32;
    #pragma unroll
    for (int k = 0; k < 8; ++k) {
      const int c = (k + qf * 2) & 7;
      wr[k] = *(const float4*)(pr + c * 4);
      wz[k] = *(const float4*)(pz + c * 4);
      wn[k] = *(const float4*)(pn + c * 4);
      ur[k] = *(const float4*)(qr + c * 4);
      uz[k] = *(const float4*)(qz + c * 4);
      un[k] = *(const float4*)(qn + c * 4);
    }
  }
  const float* bhh = role ? bhh1 : bhh0;
  const float bhr = bhh[j], bhz = bhh[j + 128], bhn = bhh[j + 256];
  float bxr = 0.f, bxz = 0.f, bxn = 0.f;
  if (role) { bxr = bih1[j]; bxz = bih1[j + 128]; bxn = bih1[j + 256]; }

  if (tid < 128) {
    hs1[0][tid] = 0.f; hs1[1][tid] = 0.f;
    hs2[0][tid] = 0.f; hs2[1][tid] = 0.f;
  }
  const float* xwb = xW + (size_t)b * 50 * 384;
  float xr = 0.f, xz = 0.f, xn = 0.f;
  if (!role && qf == 0) { xr = xwb[j]; xz = xwb[128 + j]; xn = xwb[256 + j]; }
  __syncthreads();

  int cur = 0;
  for (int t = 0; t <= 50; ++t) {
    float nxr = 0.f, nxz = 0.f, nxn = 0.f;
    if (!role && qf == 0 && t + 1 < 50) {
      const float* xwn = xwb + (size_t)(t + 1) * 384;
      nxr = xwn[j]; nxz = xwn[128 + j]; nxn = xwn[256 + j];
    }

    if (!role) {
      if (t < 50) {
        float ar = 0.f, az = 0.f, an = 0.f;
        #pragma unroll
        for (int k = 0; k < 8; ++k) {
          const int c = (k + qf * 2) & 7;
          float4 hv = *(const float4*)&hs1[cur][qf * 32 + c * 4];
          ar += wr[k].x * hv.x + wr[k].y * hv.y + wr[k].z * hv.z + wr[k].w * hv.w;
          az += wz[k].x * hv.x + wz[k].y * hv.y + wz[k].z * hv.z + wz[k].w * hv.w;
          an += wn[k].x * hv.x + wn[k].y * hv.y + wn[k].z * hv.z + wn[k].w * hv.w;
        }
        ar += __shfl_xor(ar, 1); ar += __shfl_xor(ar, 2);
        az += __shfl_xor(az, 1); az += __shfl_xor(az, 2);
        an += __shfl_xor(an, 1); an += __shfl_xor(an, 2);
        if (qf == 0) {
          float r = sigmoidf_(xr + ar + bhr);
          float z = sigmoidf_(xz + az + bhz);
          float nn = tanhf(xn + r * (an + bhn));   // bias INSIDE r*
          float h = (1.f - z) * nn + z * hs1[cur][j];
          hs1[cur ^ 1][j] = h;
        }
      }
    } else {
      if (t >= 1) {
        // h2[t-1] = f(h1[t-1] = hs1[cur], h2[t-2] = hs2[cur])
        float ar = 0.f, az = 0.f, an = 0.f;   // Whh1 @ h2[t-2]
        float sr = 0.f, sz = 0.f, sn = 0.f;   // Wih1 @ h1[t-1]
        #pragma unroll
        for (int k = 0; k < 8; ++k) {
          const int c = (k + qf * 2) & 7;
          float4 h2v = *(const float4*)&hs2[cur][qf * 32 + c * 4];
          float4 h1v = *(const float4*)&hs1[cur][qf * 32 + c * 4];
          ar += wr[k].x * h2v.x + wr[k].y * h2v.y + wr[k].z * h2v.z + wr[k].w * h2v.w;
          az += wz[k].x * h2v.x + wz[k].y * h2v.y + wz[k].z * h2v.z + wz[k].w * h2v.w;
          an += wn[k].x * h2v.x + wn[k].y * h2v.y + wn[k].z * h2v.z + wn[k].w * h2v.w;
          sr += ur[k].x * h1v.x + ur[k].y * h1v.y + ur[k].z * h1v.z + ur[k].w * h1v.w;
          sz += uz[k].x * h1v.x + uz[k].y * h1v.y + uz[k].z * h1v.z + uz[k].w * h1v.w;
          sn += un[k].x * h1v.x + un[k].y * h1v.y + un[k].z * h1v.z + un[k].w * h1v.w;
        }
        ar += __shfl_xor(ar, 1); ar += __shfl_xor(ar, 2);
        az += __shfl_xor(az, 1); az += __shfl_xor(az, 2);
        an += __shfl_xor(an, 1); an += __shfl_xor(an, 2);
        sr += __shfl_xor(sr, 1); sr += __shfl_xor(sr, 2);
        sz += __shfl_xor(sz, 1); sz += __shfl_xor(sz, 2);
        sn += __shfl_xor(sn, 1); sn += __shfl_xor(sn, 2);
        if (qf == 0) {
          float r2 = sigmoidf_(sr + bxr + ar + bhr);
          float z2 = sigmoidf_(sz + bxz + az + bhz);
          float n2 = tanhf(sn + bxn + r2 * (an + bhn));   // bias INSIDE r*
          float h2 = (1.f - z2) * n2 + z2 * hs2[cur][j];
          hs2[cur ^ 1][j] = h2;
          Hout[(size_t)(b * 50 + (t - 1)) * 128 + j] = h2;
        }
      }
    }
    __syncthreads();
    cur ^= 1;
    xr = nxr; xz = nxz; xn = nxn;
  }
}

// ---------------------------------------------------------------------------
// Attention: per (b,t) block (6400 blocks, 128 threads).
// ---------------------------------------------------------------------------
__global__ __launch_bounds__(128) void k_attn(
    const float* __restrict__ H2, const int* __restrict__ F,
    const float* __restrict__ emb, float* __restrict__ S) {
  const int m = blockIdx.x;
  const int tid = threadIdx.x;
  __shared__ __align__(16) float outs[128];
  __shared__ __align__(16) float Ls[64][132];
  __shared__ float hls[64];
  __shared__ float wts[64];
  __shared__ int fs[64];

  outs[tid] = H2[(size_t)m * 128 + tid];
  if (tid < 64) fs[tid] = F[(size_t)m * 64 + tid];
  __syncthreads();

  #pragma unroll
  for (int i = 0; i < 16; ++i) {
    int idx = tid + i * 128;
    int a = idx >> 5, c4 = idx & 31;
    float4 v = *(const float4*)&emb[(size_t)fs[a] * 128 + c4 * 4];
    *(float4*)&Ls[a][c4 * 4] = v;
  }
  __syncthreads();

  {
    const int a = tid >> 1, hf = tid & 1;
    float sum = 0.f;
    #pragma unroll
    for (int j = 0; j < 16; ++j) {
      float4 lv = *(const float4*)&Ls[a][hf * 64 + j * 4];
      float4 ov = *(const float4*)&outs[hf * 64 + j * 4];
      sum += lv.x * ov.x + lv.y * ov.y + lv.z * ov.z + lv.w * ov.w;
    }
    float other = __shfl_xor(sum, 1);
    sum += other;
    if (hf == 0) hls[a] = sum + (fs[a] > 0 ? 0.0f : -1e30f);
  }
  __syncthreads();

  if (tid < 64) {
    float v = hls[tid];
    float mx = v;
    #pragma unroll
    for (int o = 32; o; o >>= 1) mx = fmaxf(mx, __shfl_xor(mx, o));
    float e = __expf(v - mx);
    float sm = e;
    #pragma unroll
    for (int o = 32; o; o >>= 1) sm += __shfl_xor(sm, o);
    wts[tid] = e / sm;
  }
  __syncthreads();

  float kv = 0.f;
  #pragma unroll 8
  for (int a2 = 0; a2 < 64; ++a2) kv += wts[a2] * Ls[a2][tid];

  S[(size_t)m * 256 + tid] = outs[tid];
  S[(size_t)m * 256 + 128 + tid] = kv;
}

// ---------------------------------------------------------------------------
extern "C" void kernel_launch(void* const* d_in, const int* in_sizes, int n_in,
                              void* d_out, int out_size, void* d_ws, size_t ws_size,
                              hipStream_t stream) {
  const float* inputs_x  = (const float*)d_in[0];
  const int*   inputs_f  = (const int*)d_in[1];
  const float* mask_seqs = (const float*)d_in[2];
  const float* dag_emb   = (const float*)d_in[3];
  const float* embed_a   = (const float*)d_in[4];
  const float* Wih0 = (const float*)d_in[5];
  const float* Whh0 = (const float*)d_in[6];
  const float* bih0 = (const float*)d_in[7];
  const float* bhh0 = (const float*)d_in[8];
  const float* Wih1 = (const float*)d_in[9];
  const float* Whh1 = (const float*)d_in[10];
  const float* bih1 = (const float*)d_in[11];
  const float* bhh1 = (const float*)d_in[12];
  const float* fc_w = (const float*)d_in[13];
  const float* fc_b = (const float*)d_in[14];
  float* out = (float*)d_out;

  float* ws = (float*)d_ws;
  // P: KSPLIT(=10) slots of 819200; X aliases P0; S aliases P1-2 (P dead
  // after reduce). Total 10*819200 + 2457600 + 2*819200 = 12.29M floats (49MB).
  float* P  = ws;
  float* X  = P;                       // aliases P slot 0 (reduce in-place safe)
  float* S  = P + 819200;              // aliases P slots 1-2 (P dead after reduce)
  float* xW = ws + KSPLIT * 819200;
  float* H1 = xW + 2457600;            // region kept for Wt alias; H1 itself unused (fused GRU)
  float* H2 = H1 + 819200;
  // Wt (2.5 MB bf16) aliases H1 region start; H2 at +3.28MB is beyond Wt.
  unsigned short* Wt = (unsigned short*)H1;

  k_prep_wt<<<306, 256, 0, stream>>>(dag_emb, Wt);
  k_gemm_mfma<<<dim3(50, KSPLIT), 512, 0, stream>>>(inputs_x, Wt, P);
  k_reduce_tanh<<<800, 256, 0, stream>>>(P, X);
  k_gemm_bn<128, 0><<<dim3(200, 6), 256, 0, stream>>>(X, Wih0, bih0, nullptr, xW, 384, 384);
  k_gru2<<<128, 1024, 0, stream>>>(xW, Whh0, bhh0, Wih1, bih1, Whh1, bhh1, H2);
  k_attn<<<6400, 128, 0, stream>>>(H2, inputs_f, embed_a, S);
  k_gemm_bn<256, 1><<<dim3(200, 5), 256, 0, stream>>>(S, fc_w, fc_b, mask_seqs, out, 283, 283);
}

// Round 6
// 492.463 us; speedup vs baseline: 2.6605x; 2.6605x over previous
//
#include <hip/hip_runtime.h>
#include <math.h>

#define B_DIM 128
#define T_DIM 50
#define LEAF  4880
#define A_DIM 64
#define ATTN  128
#define RNN   128
#define NC    283
#define M_TOT (B_DIM*T_DIM)   // 6400
#define KSPLIT 10
#define NCH 153               // ceil(4880/32); chunk 152 has 16 valid k
#define WT_PLANE (NCH*512*8)  // 626688 ushort per plane (hi / lo)

using short8 = __attribute__((ext_vector_type(8))) short;
using f32x4  = __attribute__((ext_vector_type(4))) float;

__device__ __forceinline__ float sigmoidf_(float x) {
  return 1.0f / (1.0f + __expf(-x));
}

// RNE fp32 -> bf16 bits
__device__ __forceinline__ unsigned short f32_to_bf16_rne(float f) {
  unsigned int u = __float_as_uint(f);
  unsigned int r = u + 0x7FFFu + ((u >> 16) & 1u);
  return (unsigned short)(r >> 16);
}
__device__ __forceinline__ float bf16_bits_to_f32(unsigned short b) {
  return __uint_as_float(((unsigned int)b) << 16);
}

// ---------------------------------------------------------------------------
// Pre-transpose W[4880,128] into MFMA B-fragment order, hi/lo bf16 planes.
// ---------------------------------------------------------------------------
__global__ __launch_bounds__(256) void k_prep_wt(
    const float* __restrict__ Wd, unsigned short* __restrict__ Wt) {
  const int u = blockIdx.x * 256 + threadIdx.x;   // 0 .. 78335 (NCH*512)
  const int c = u >> 9, rem = u & 511;
  const int nt = rem >> 6, lane = rem & 63;
  const int n = nt * 16 + (lane & 15);
  const int kb = c * 32 + ((lane >> 4) << 3);
  short8 h8, l8;
  #pragma unroll
  for (int j = 0; j < 8; ++j) {
    int k = kb + j;
    float v = (k < LEAF) ? Wd[(size_t)k * 128 + n] : 0.0f;
    unsigned short hb = f32_to_bf16_rne(v);
    unsigned short lb = f32_to_bf16_rne(v - bf16_bits_to_f32(hb));
    h8[j] = (short)hb;
    l8[j] = (short)lb;
  }
  *(short8*)&Wt[(size_t)u * 8] = h8;
  *(short8*)&Wt[(size_t)WT_PLANE + (size_t)u * 8] = l8;
}

// ---------------------------------------------------------------------------
// Big GEMM via MFMA, v7: BM=128, KSPLIT=10 (R11 carried; R12 keeps it).
// R10 proved the latency model (BM 32->64 = -18us on-model):
// time ~ total-wave-chunks x per-wave-chunk-serial-latency / 1024 SIMDs.
// v7 halves wave-chunks again (61,200); predict ~45-50us. KSPLIT=10 keeps
// grid=500 (2 blocks/CU at 32KB LDS dbuf). A staging: 4 threads/row x 8
// floats -> vmcnt entry set = [B(c)x2, A(c+1)x2], waits 4/2/0.
// Arithmetic identical (3-MFMA hi/lo) -> absmax bit-identical.
// ---------------------------------------------------------------------------
__global__ __launch_bounds__(512, 4) void k_gemm_mfma(
    const float* __restrict__ Ax, const unsigned short* __restrict__ Wt,
    float* __restrict__ P) {
  __shared__ __align__(16) unsigned short As[2][8192];  // 32 KB [buf][plane*4096 + frag]
  const int tid  = threadIdx.x;
  const int lane = tid & 63;
  const int w    = tid >> 6;     // wave id = nt tile (16 cols each)
  const int M0   = blockIdx.x * 128;
  const int s    = blockIdx.y;
  const int c0   = (s * NCH) / KSPLIT;
  const int c1   = ((s + 1) * NCH) / KSPLIT;

  // A staging map: row am = tid>>2 (0..127), k-octet kq = tid&3.
  // 4 threads cover one row's 32 floats (128B contiguous, coalesced).
  const int am = tid >> 2;
  const int kq = tid & 3;
  const float* pA = Ax + (size_t)(M0 + am) * LEAF;
  // ushort index (within plane) matching the MFMA A-fragment read layout:
  // elem A[row][k] lives at (row>>4)*512 + ((row&15) + 16*(k>>3))*8 + (k&7)
  const int a_idx = (am >> 4) * 512 + ((am & 15) + 16 * kq) * 8;

  f32x4 acc[8];
  #pragma unroll
  for (int i = 0; i < 8; ++i) {
    #pragma unroll
    for (int q = 0; q < 4; ++q) acc[i][q] = 0.0f;
  }

  float4 rA_a0, rA_a1, rA_b0, rA_b1;   // ping-pong A prefetch (depth 2, 8 floats each)
  short8 bh_a, bl_a, bh_b, bl_b;       // ping-pong B fragments (depth 1)

  auto issueB = [&](int c, short8& bh, short8& bl) {
    const size_t o = ((size_t)c * 512 + w * 64 + lane) * 8;
    bh = *(const short8*)&Wt[o];
    bl = *(const short8*)&Wt[(size_t)WT_PLANE + o];
  };
  auto issueA = [&](int c, float4& r0, float4& r1) {
    int kk = c * 32 + kq * 8;
    kk = min(kk, LEAF - 8);            // clamp (no skip): uniform vmcnt counts;
    r0 = *(const float4*)(pA + kk);    // clamped dup data x Wt zero rows = 0
    r1 = *(const float4*)(pA + kk + 4);
  };
  auto storeA = [&](int p, float4 r0, float4 r1) {
    float v[8] = {r0.x, r0.y, r0.z, r0.w, r1.x, r1.y, r1.z, r1.w};
    short8 h8, l8;
    #pragma unroll
    for (int j = 0; j < 8; ++j) {
      unsigned short hb = f32_to_bf16_rne(v[j]);
      unsigned short lb = f32_to_bf16_rne(v[j] - bf16_bits_to_f32(hb));
      h8[j] = (short)hb;
      l8[j] = (short)lb;
    }
    *(short8*)&As[p][a_idx] = h8;
    *(short8*)&As[p][4096 + a_idx] = l8;
  };
  auto compute = [&](int p, const short8& bh, const short8& bl) {
    #pragma unroll
    for (int m = 0; m < 8; ++m) {
      short8 a_hi = *(const short8*)&As[p][m * 512 + lane * 8];
      short8 a_lo = *(const short8*)&As[p][4096 + m * 512 + lane * 8];
      acc[m] = __builtin_amdgcn_mfma_f32_16x16x32_bf16(a_hi, bl, acc[m], 0, 0, 0);
      acc[m] = __builtin_amdgcn_mfma_f32_16x16x32_bf16(a_lo, bh, acc[m], 0, 0, 0);
      acc[m] = __builtin_amdgcn_mfma_f32_16x16x32_bf16(a_hi, bh, acc[m], 0, 0, 0);
    }
  };

  // ---- prologue ----
  {
    float4 t0, t1;
    issueA(c0, t0, t1);
    asm volatile("s_waitcnt vmcnt(0)" ::: "memory");
    storeA(0, t0, t1);
    issueB(c0, bh_a, bl_a);                          // 2 loads
    asm volatile("" ::: "memory");
    if (c0 + 1 < c1) issueA(c0 + 1, rA_a0, rA_a1);   // 2 loads
    asm volatile("s_waitcnt lgkmcnt(0)" ::: "memory");
    __builtin_amdgcn_s_barrier();
    asm volatile("" ::: "memory");
    // outstanding entering loop: [B(c0) x2, A(c0+1) x2]
  }

  // Per iter: outstanding on entry = [B(c)x2, A(c+1)x2] (from prev iter).
  // Issue B(c+1)x2, A(c+2)x2; counted wait drains exactly the entry set;
  // compute with B(c); storeA(A(c+1)); lgkm; barrier.
#define GEMM_ITER(BHc, BLc, BHn, BLn, RAc0, RAc1, RAn0, RAn1)                 \
  {                                                                           \
    const int p = (c - c0) & 1;                                               \
    const bool has1 = (c + 1 < c1), has2 = (c + 2 < c1);                      \
    if (has1) { issueB(c + 1, BHn, BLn); asm volatile("" ::: "memory"); }     \
    if (has2) { issueA(c + 2, RAn0, RAn1); asm volatile("" ::: "memory"); }   \
    if (has1) {                                                               \
      if (has2) { asm volatile("s_waitcnt vmcnt(4)" ::: "memory"); }          \
      else      { asm volatile("s_waitcnt vmcnt(2)" ::: "memory"); }          \
    } else      { asm volatile("s_waitcnt vmcnt(0)" ::: "memory"); }          \
    compute(p, BHc, BLc);                                                     \
    if (has1) storeA(p ^ 1, RAc0, RAc1);                                      \
    asm volatile("s_waitcnt lgkmcnt(0)" ::: "memory");                        \
    __builtin_amdgcn_s_barrier();                                             \
    asm volatile("" ::: "memory");                                            \
    ++c;                                                                      \
  }

  int c = c0;
  while (c < c1) {
    GEMM_ITER(bh_a, bl_a, bh_b, bl_b, rA_a0, rA_a1, rA_b0, rA_b1);
    if (c < c1) GEMM_ITER(bh_b, bl_b, bh_a, bl_a, rA_b0, rA_b1, rA_a0, rA_a1);
  }
#undef GEMM_ITER

  // epilogue: C/D layout col=lane&15, row=(lane>>4)*4+r ; cols = w*16..w*16+15
  float* outp = P + (size_t)s * ((size_t)M_TOT * 128);
  const int col0 = w * 16 + (lane & 15);
  #pragma unroll
  for (int m = 0; m < 8; ++m) {
    const int rbase = M0 + m * 16 + ((lane >> 4) << 2);
    #pragma unroll
    for (int r = 0; r < 4; ++r)
      outp[(size_t)(rbase + r) * 128 + col0] = acc[m][r];
  }
}

// ---------------------------------------------------------------------------
// Reduce KSPLIT partials + tanh (X aliases P slot 0; elementwise-safe).
// ---------------------------------------------------------------------------
__global__ __launch_bounds__(256) void k_reduce_tanh(
    float* __restrict__ P, float* __restrict__ X) {
  const size_t i = ((size_t)blockIdx.x * 256 + threadIdx.x) * 4;
  float4 a = *(const float4*)&P[i];
  #pragma unroll
  for (int s = 1; s < KSPLIT; ++s) {
    float4 b = *(const float4*)&P[(size_t)s * (M_TOT * 128) + i];
    a.x += b.x; a.y += b.y; a.z += b.z; a.w += b.w;
  }
  a.x = tanhf(a.x); a.y = tanhf(a.y); a.z = tanhf(a.z); a.w = tanhf(a.w);
  *(float4*)&X[i] = a;
}

// ---------------------------------------------------------------------------
// Generic small GEMM: C[M,N] = A[M,K] @ Bw[N,K]^T + bias  (opt sigmoid*mask)
// ---------------------------------------------------------------------------
template<int K, int ACT>
__global__ __launch_bounds__(256) void k_gemm_bn(
    const float* __restrict__ A, const float* __restrict__ Bw,
    const float* __restrict__ bias, const float* __restrict__ maskv,
    float* __restrict__ C, int N, int ldc) {
  __shared__ __align__(16) float Asm[32][K + 4];
  const int tid = threadIdx.x;
  const int m0 = blockIdx.x * 32;
  const int n0 = blockIdx.y * 64;
  constexpr int K4 = K / 4;

  #pragma unroll
  for (int i = 0; i < (32 * K4) / 256; ++i) {
    int idx = tid + i * 256;
    int row = idx / K4, k4 = idx % K4;
    float4 v = *(const float4*)&A[(size_t)(m0 + row) * K + k4 * 4];
    *(float4*)&Asm[row][k4 * 4] = v;
  }
  __syncthreads();

  const int n2 = tid & 31, mg = tid >> 5;
  const int n = n0 + n2 * 2;
  const int ns0 = min(n, N - 1), ns1 = min(n + 1, N - 1);
  const float* Bp0 = Bw + (size_t)ns0 * K;
  const float* Bp1 = Bw + (size_t)ns1 * K;

  float acc[4][2] = {};
  #pragma unroll 4
  for (int k = 0; k < K; k += 4) {
    float4 b0 = *(const float4*)&Bp0[k];
    float4 b1 = *(const float4*)&Bp1[k];
    #pragma unroll
    for (int r = 0; r < 4; ++r) {
      float4 a = *(const float4*)&Asm[mg * 4 + r][k];
      acc[r][0] += a.x * b0.x + a.y * b0.y + a.z * b0.z + a.w * b0.w;
      acc[r][1] += a.x * b1.x + a.y * b1.y + a.z * b1.z + a.w * b1.w;
    }
  }

  #pragma unroll
  for (int r = 0; r < 4; ++r) {
    int m = m0 + mg * 4 + r;
    #pragma unroll
    for (int c = 0; c < 2; ++c) {
      int nn = n + c;
      if (nn < N) {
        float v = acc[r][c] + bias[nn];
        if (ACT) v = sigmoidf_(v) * maskv[m];
        C[(size_t)m * ldc + nn] = v;
      }
    }
  }
}

// ---------------------------------------------------------------------------
// GRU scan v3 (R5-proven, restored after R11's fused-GRU register-spill
// catastrophe: 1024t block needed 192 VGPR/thread > 2048/16-wave budget ->
// compiler spilled all weights to scratch, FETCH 1.6GB, 962us. Budget rule:
// waves/block x regs/thread <= 2048.) One block per batch row; 512 threads.
// Weights pre-rotated at load (register arrays use unroll-constant indices
// only). n-gate bias INSIDE r*: n = tanh(xn + r*(Wn.h + bn)).
// ---------------------------------------------------------------------------
__global__ __launch_bounds__(512) void k_gru(
    const float* __restrict__ xW, const float* __restrict__ Whh,
    const float* __restrict__ bhh, float* __restrict__ Hout) {
  const int b = blockIdx.x;
  const int tid = threadIdx.x;
  const int j  = tid >> 2;
  const int qf = tid & 3;
  __shared__ __align__(16) float hs[2][128];

  float4 wr[8], wz[8], wn[8];
  {
    const float* pr = Whh + (size_t)j * 128 + qf * 32;
    const float* pz = Whh + (size_t)(j + 128) * 128 + qf * 32;
    const float* pn = Whh + (size_t)(j + 256) * 128 + qf * 32;
    #pragma unroll
    for (int k = 0; k < 8; ++k) {
      const int c = (k + qf * 2) & 7;   // rotation folded into the LOAD
      wr[k] = *(const float4*)(pr + c * 4);
      wz[k] = *(const float4*)(pz + c * 4);
      wn[k] = *(const float4*)(pn + c * 4);
    }
  }
  const float br = bhh[j], bz = bhh[j + 128], bn_ = bhh[j + 256];

  if (tid < 128) hs[0][tid] = 0.0f;
  const float* xwb = xW + (size_t)b * 50 * 384;
  float xr = 0.f, xz = 0.f, xn = 0.f;
  if (qf == 0) { xr = xwb[j]; xz = xwb[128 + j]; xn = xwb[256 + j]; }
  __syncthreads();

  int cur = 0;
  for (int t = 0; t < 50; ++t) {
    float nxr = 0.f, nxz = 0.f, nxn = 0.f;
    if (qf == 0 && t + 1 < 50) {
      const float* xwn = xwb + (size_t)(t + 1) * 384;
      nxr = xwn[j]; nxz = xwn[128 + j]; nxn = xwn[256 + j];
    }

    float ar = 0.f, az = 0.f, an = 0.f;
    #pragma unroll
    for (int k = 0; k < 8; ++k) {
      const int c = (k + qf * 2) & 7;   // runtime -> LDS address only
      float4 hv = *(const float4*)&hs[cur][qf * 32 + c * 4];
      ar += wr[k].x * hv.x + wr[k].y * hv.y + wr[k].z * hv.z + wr[k].w * hv.w;
      az += wz[k].x * hv.x + wz[k].y * hv.y + wz[k].z * hv.z + wz[k].w * hv.w;
      an += wn[k].x * hv.x + wn[k].y * hv.y + wn[k].z * hv.z + wn[k].w * hv.w;
    }
    ar += __shfl_xor(ar, 1); ar += __shfl_xor(ar, 2);
    az += __shfl_xor(az, 1); az += __shfl_xor(az, 2);
    an += __shfl_xor(an, 1); an += __shfl_xor(an, 2);

    if (qf == 0) {
      float r = sigmoidf_(xr + ar + br);
      float z = sigmoidf_(xz + az + bz);
      float nn = tanhf(xn + r * (an + bn_));   // bias INSIDE r*
      float h = (1.f - z) * nn + z * hs[cur][j];
      hs[cur ^ 1][j] = h;
      Hout[(size_t)(b * 50 + t) * 128 + j] = h;
    }
    __syncthreads();
    cur ^= 1;
    xr = nxr; xz = nxz; xn = nxn;
  }
}

// ---------------------------------------------------------------------------
// Attention: per (b,t) block (6400 blocks, 128 threads).
// ---------------------------------------------------------------------------
__global__ __launch_bounds__(128) void k_attn(
    const float* __restrict__ H2, const int* __restrict__ F,
    const float* __restrict__ emb, float* __restrict__ S) {
  const int m = blockIdx.x;
  const int tid = threadIdx.x;
  __shared__ __align__(16) float outs[128];
  __shared__ __align__(16) float Ls[64][132];
  __shared__ float hls[64];
  __shared__ float wts[64];
  __shared__ int fs[64];

  outs[tid] = H2[(size_t)m * 128 + tid];
  if (tid < 64) fs[tid] = F[(size_t)m * 64 + tid];
  __syncthreads();

  #pragma unroll
  for (int i = 0; i < 16; ++i) {
    int idx = tid + i * 128;
    int a = idx >> 5, c4 = idx & 31;
    float4 v = *(const float4*)&emb[(size_t)fs[a] * 128 + c4 * 4];
    *(float4*)&Ls[a][c4 * 4] = v;
  }
  __syncthreads();

  {
    const int a = tid >> 1, hf = tid & 1;
    float sum = 0.f;
    #pragma unroll
    for (int j = 0; j < 16; ++j) {
      float4 lv = *(const float4*)&Ls[a][hf * 64 + j * 4];
      float4 ov = *(const float4*)&outs[hf * 64 + j * 4];
      sum += lv.x * ov.x + lv.y * ov.y + lv.z * ov.z + lv.w * ov.w;
    }
    float other = __shfl_xor(sum, 1);
    sum += other;
    if (hf == 0) hls[a] = sum + (fs[a] > 0 ? 0.0f : -1e30f);
  }
  __syncthreads();

  if (tid < 64) {
    float v = hls[tid];
    float mx = v;
    #pragma unroll
    for (int o = 32; o; o >>= 1) mx = fmaxf(mx, __shfl_xor(mx, o));
    float e = __expf(v - mx);
    float sm = e;
    #pragma unroll
    for (int o = 32; o; o >>= 1) sm += __shfl_xor(sm, o);
    wts[tid] = e / sm;
  }
  __syncthreads();

  float kv = 0.f;
  #pragma unroll 8
  for (int a2 = 0; a2 < 64; ++a2) kv += wts[a2] * Ls[a2][tid];

  S[(size_t)m * 256 + tid] = outs[tid];
  S[(size_t)m * 256 + 128 + tid] = kv;
}

// ---------------------------------------------------------------------------
extern "C" void kernel_launch(void* const* d_in, const int* in_sizes, int n_in,
                              void* d_out, int out_size, void* d_ws, size_t ws_size,
                              hipStream_t stream) {
  const float* inputs_x  = (const float*)d_in[0];
  const int*   inputs_f  = (const int*)d_in[1];
  const float* mask_seqs = (const float*)d_in[2];
  const float* dag_emb   = (const float*)d_in[3];
  const float* embed_a   = (const float*)d_in[4];
  const float* Wih0 = (const float*)d_in[5];
  const float* Whh0 = (const float*)d_in[6];
  const float* bih0 = (const float*)d_in[7];
  const float* bhh0 = (const float*)d_in[8];
  const float* Wih1 = (const float*)d_in[9];
  const float* Whh1 = (const float*)d_in[10];
  const float* bih1 = (const float*)d_in[11];
  const float* bhh1 = (const float*)d_in[12];
  const float* fc_w = (const float*)d_in[13];
  const float* fc_b = (const float*)d_in[14];
  float* out = (float*)d_out;

  float* ws = (float*)d_ws;
  // P: KSPLIT(=10) slots of 819200; X aliases P0; S aliases P1-2 (P dead
  // after reduce). Total 10*819200 + 2457600 + 2*819200 = 12.29M floats (49MB).
  float* P  = ws;
  float* X  = P;                       // aliases P slot 0 (reduce in-place safe)
  float* S  = P + 819200;              // aliases P slots 1-2 (P dead after reduce)
  float* xW = ws + KSPLIT * 819200;
  float* H1 = xW + 2457600;
  float* H2 = H1 + 819200;
  // Wt (2.5 MB bf16) aliases H1+H2 (6.5 MB): dead before k_gru writes H1.
  unsigned short* Wt = (unsigned short*)H1;

  k_prep_wt<<<306, 256, 0, stream>>>(dag_emb, Wt);
  k_gemm_mfma<<<dim3(50, KSPLIT), 512, 0, stream>>>(inputs_x, Wt, P);
  k_reduce_tanh<<<800, 256, 0, stream>>>(P, X);
  k_gemm_bn<128, 0><<<dim3(200, 6), 256, 0, stream>>>(X, Wih0, bih0, nullptr, xW, 384, 384);
  k_gru<<<128, 512, 0, stream>>>(xW, Whh0, bhh0, H1);
  k_gemm_bn<128, 0><<<dim3(200, 6), 256, 0, stream>>>(H1, Wih1, bih1, nullptr, xW, 384, 384);
  k_gru<<<128, 512, 0, stream>>>(xW, Whh1, bhh1, H2);
  k_attn<<<6400, 128, 0, stream>>>(H2, inputs_f, embed_a, S);
  k_gemm_bn<256, 1><<<dim3(200, 5), 256, 0, stream>>>(S, fc_w, fc_b, mask_seqs, out, 283, 283);
}

// Round 7
// 371.464 us; speedup vs baseline: 3.5271x; 1.3257x over previous
//
#include <hip/hip_runtime.h>
#include <math.h>

#define B_DIM 128
#define T_DIM 50
#define LEAF  4880
#define A_DIM 64
#define ATTN  128
#define RNN   128
#define NC    283
#define M_TOT (B_DIM*T_DIM)   // 6400
#define KSPLIT 10
#define NCH 153               // ceil(4880/32); chunk 152 has 16 valid k
#define WT_PLANE (NCH*512*8)  // 626688 ushort per plane (hi / lo)

using short8 = __attribute__((ext_vector_type(8))) short;
using short4v = __attribute__((ext_vector_type(4))) short;
using f32x4  = __attribute__((ext_vector_type(4))) float;

__device__ __forceinline__ float sigmoidf_(float x) {
  return 1.0f / (1.0f + __expf(-x));
}

// RNE fp32 -> bf16 bits
__device__ __forceinline__ unsigned short f32_to_bf16_rne(float f) {
  unsigned int u = __float_as_uint(f);
  unsigned int r = u + 0x7FFFu + ((u >> 16) & 1u);
  return (unsigned short)(r >> 16);
}
__device__ __forceinline__ float bf16_bits_to_f32(unsigned short b) {
  return __uint_as_float(((unsigned int)b) << 16);
}

// ---------------------------------------------------------------------------
// Unified prep: (a) W[4880,128] -> Wt MFMA B-fragment order (hi/lo planes),
// (b) R13: Wih0/Wih1/fc_w -> Bt0/Bt1/Bt2 fragment order for the bn-MFMA
// kernels (nt padded to 24; n >= N rows zeroed so padded tiles are inert).
// ---------------------------------------------------------------------------
__global__ __launch_bounds__(256) void k_prep(
    const float* __restrict__ Wd,
    const float* __restrict__ Wih0, const float* __restrict__ Wih1,
    const float* __restrict__ fcw,
    unsigned short* __restrict__ Wt,
    unsigned short* __restrict__ Bt0, unsigned short* __restrict__ Bt1,
    unsigned short* __restrict__ Bt2) {
  const int bx = blockIdx.x;
  const int tid = threadIdx.x;
  if (bx < 306) {
    const int u = bx * 256 + tid;   // 0 .. 78335 (NCH*512)
    const int c = u >> 9, rem = u & 511;
    const int nt = rem >> 6, lane = rem & 63;
    const int n = nt * 16 + (lane & 15);
    const int kb = c * 32 + ((lane >> 4) << 3);
    short8 h8, l8;
    #pragma unroll
    for (int j = 0; j < 8; ++j) {
      int k = kb + j;
      float v = (k < LEAF) ? Wd[(size_t)k * 128 + n] : 0.0f;
      unsigned short hb = f32_to_bf16_rne(v);
      unsigned short lb = f32_to_bf16_rne(v - bf16_bits_to_f32(hb));
      h8[j] = (short)hb;
      l8[j] = (short)lb;
    }
    *(short8*)&Wt[(size_t)u * 8] = h8;
    *(short8*)&Wt[(size_t)WT_PLANE + (size_t)u * 8] = l8;
  } else {
    // Bt prep: slot s -> (kc, nt, lane); elem: n = nt*16+(lane&15),
    // k = kc*32 + ((lane>>4)<<3) + j. Plane size PL = (K/32)*24*512.
    const float* src; unsigned short* dst; int N, K, s0;
    if (bx < 330)      { src = Wih0; dst = Bt0; N = 384; K = 128; s0 = (bx - 306) * 256; }
    else if (bx < 354) { src = Wih1; dst = Bt1; N = 384; K = 128; s0 = (bx - 330) * 256; }
    else               { src = fcw;  dst = Bt2; N = NC;  K = 256; s0 = (bx - 354) * 256; }
    const int s = s0 + tid;
    const int PL = (K / 32) * 24 * 512;
    const int kc = s / (24 * 64);
    const int r  = s % (24 * 64);
    const int nt = r >> 6, lane = r & 63;
    const int n  = nt * 16 + (lane & 15);
    const int kb = kc * 32 + ((lane >> 4) << 3);
    short8 h8, l8;
    #pragma unroll
    for (int j = 0; j < 8; ++j) {
      float v = (n < N) ? src[(size_t)n * K + kb + j] : 0.0f;
      unsigned short hb = f32_to_bf16_rne(v);
      unsigned short lb = f32_to_bf16_rne(v - bf16_bits_to_f32(hb));
      h8[j] = (short)hb;
      l8[j] = (short)lb;
    }
    *(short8*)&dst[(size_t)s * 8] = h8;
    *(short8*)&dst[(size_t)PL + (size_t)s * 8] = l8;
  }
}

// ---------------------------------------------------------------------------
// Big GEMM via MFMA, v7: BM=128, KSPLIT=10 (R12: == v6 within noise; the
// BM lever is exhausted -- kernel at its fixed-per-chunk floor ~55us).
// Latency model (R10-proven): time ~ wave-chunks x serial-latency / 1024.
// A staging: 4 threads/row x 8 floats -> vmcnt entry set = [B(c)x2, A(c+1)x2],
// waits 4/2/0. Arithmetic: 3-MFMA hi/lo -> absmax bit-identical.
// ---------------------------------------------------------------------------
__global__ __launch_bounds__(512, 4) void k_gemm_mfma(
    const float* __restrict__ Ax, const unsigned short* __restrict__ Wt,
    float* __restrict__ P) {
  __shared__ __align__(16) unsigned short As[2][8192];  // 32 KB [buf][plane*4096 + frag]
  const int tid  = threadIdx.x;
  const int lane = tid & 63;
  const int w    = tid >> 6;     // wave id = nt tile (16 cols each)
  const int M0   = blockIdx.x * 128;
  const int s    = blockIdx.y;
  const int c0   = (s * NCH) / KSPLIT;
  const int c1   = ((s + 1) * NCH) / KSPLIT;

  // A staging map: row am = tid>>2 (0..127), k-octet kq = tid&3.
  const int am = tid >> 2;
  const int kq = tid & 3;
  const float* pA = Ax + (size_t)(M0 + am) * LEAF;
  // elem A[row][k] lives at (row>>4)*512 + ((row&15) + 16*(k>>3))*8 + (k&7)
  const int a_idx = (am >> 4) * 512 + ((am & 15) + 16 * kq) * 8;

  f32x4 acc[8];
  #pragma unroll
  for (int i = 0; i < 8; ++i) {
    #pragma unroll
    for (int q = 0; q < 4; ++q) acc[i][q] = 0.0f;
  }

  float4 rA_a0, rA_a1, rA_b0, rA_b1;   // ping-pong A prefetch (depth 2, 8 floats each)
  short8 bh_a, bl_a, bh_b, bl_b;       // ping-pong B fragments (depth 1)

  auto issueB = [&](int c, short8& bh, short8& bl) {
    const size_t o = ((size_t)c * 512 + w * 64 + lane) * 8;
    bh = *(const short8*)&Wt[o];
    bl = *(const short8*)&Wt[(size_t)WT_PLANE + o];
  };
  auto issueA = [&](int c, float4& r0, float4& r1) {
    int kk = c * 32 + kq * 8;
    kk = min(kk, LEAF - 8);            // clamp (no skip): uniform vmcnt counts;
    r0 = *(const float4*)(pA + kk);    // clamped dup data x Wt zero rows = 0
    r1 = *(const float4*)(pA + kk + 4);
  };
  auto storeA = [&](int p, float4 r0, float4 r1) {
    float v[8] = {r0.x, r0.y, r0.z, r0.w, r1.x, r1.y, r1.z, r1.w};
    short8 h8, l8;
    #pragma unroll
    for (int j = 0; j < 8; ++j) {
      unsigned short hb = f32_to_bf16_rne(v[j]);
      unsigned short lb = f32_to_bf16_rne(v[j] - bf16_bits_to_f32(hb));
      h8[j] = (short)hb;
      l8[j] = (short)lb;
    }
    *(short8*)&As[p][a_idx] = h8;
    *(short8*)&As[p][4096 + a_idx] = l8;
  };
  auto compute = [&](int p, const short8& bh, const short8& bl) {
    #pragma unroll
    for (int m = 0; m < 8; ++m) {
      short8 a_hi = *(const short8*)&As[p][m * 512 + lane * 8];
      short8 a_lo = *(const short8*)&As[p][4096 + m * 512 + lane * 8];
      acc[m] = __builtin_amdgcn_mfma_f32_16x16x32_bf16(a_hi, bl, acc[m], 0, 0, 0);
      acc[m] = __builtin_amdgcn_mfma_f32_16x16x32_bf16(a_lo, bh, acc[m], 0, 0, 0);
      acc[m] = __builtin_amdgcn_mfma_f32_16x16x32_bf16(a_hi, bh, acc[m], 0, 0, 0);
    }
  };

  // ---- prologue ----
  {
    float4 t0, t1;
    issueA(c0, t0, t1);
    asm volatile("s_waitcnt vmcnt(0)" ::: "memory");
    storeA(0, t0, t1);
    issueB(c0, bh_a, bl_a);                          // 2 loads
    asm volatile("" ::: "memory");
    if (c0 + 1 < c1) issueA(c0 + 1, rA_a0, rA_a1);   // 2 loads
    asm volatile("s_waitcnt lgkmcnt(0)" ::: "memory");
    __builtin_amdgcn_s_barrier();
    asm volatile("" ::: "memory");
    // outstanding entering loop: [B(c0) x2, A(c0+1) x2]
  }

#define GEMM_ITER(BHc, BLc, BHn, BLn, RAc0, RAc1, RAn0, RAn1)                 \
  {                                                                           \
    const int p = (c - c0) & 1;                                               \
    const bool has1 = (c + 1 < c1), has2 = (c + 2 < c1);                      \
    if (has1) { issueB(c + 1, BHn, BLn); asm volatile("" ::: "memory"); }     \
    if (has2) { issueA(c + 2, RAn0, RAn1); asm volatile("" ::: "memory"); }   \
    if (has1) {                                                               \
      if (has2) { asm volatile("s_waitcnt vmcnt(4)" ::: "memory"); }          \
      else      { asm volatile("s_waitcnt vmcnt(2)" ::: "memory"); }          \
    } else      { asm volatile("s_waitcnt vmcnt(0)" ::: "memory"); }          \
    compute(p, BHc, BLc);                                                     \
    if (has1) storeA(p ^ 1, RAc0, RAc1);                                      \
    asm volatile("s_waitcnt lgkmcnt(0)" ::: "memory");                        \
    __builtin_amdgcn_s_barrier();                                             \
    asm volatile("" ::: "memory");                                            \
    ++c;                                                                      \
  }

  int c = c0;
  while (c < c1) {
    GEMM_ITER(bh_a, bl_a, bh_b, bl_b, rA_a0, rA_a1, rA_b0, rA_b1);
    if (c < c1) GEMM_ITER(bh_b, bl_b, bh_a, bl_a, rA_b0, rA_b1, rA_a0, rA_a1);
  }
#undef GEMM_ITER

  // epilogue: C/D layout col=lane&15, row=(lane>>4)*4+r ; cols = w*16..w*16+15
  float* outp = P + (size_t)s * ((size_t)M_TOT * 128);
  const int col0 = w * 16 + (lane & 15);
  #pragma unroll
  for (int m = 0; m < 8; ++m) {
    const int rbase = M0 + m * 16 + ((lane >> 4) << 2);
    #pragma unroll
    for (int r = 0; r < 4; ++r)
      outp[(size_t)(rbase + r) * 128 + col0] = acc[m][r];
  }
}

// ---------------------------------------------------------------------------
// Reduce KSPLIT partials + tanh (X aliases P slot 0; elementwise-safe).
// ---------------------------------------------------------------------------
__global__ __launch_bounds__(256) void k_reduce_tanh(
    float* __restrict__ P, float* __restrict__ X) {
  const size_t i = ((size_t)blockIdx.x * 256 + threadIdx.x) * 4;
  float4 a = *(const float4*)&P[i];
  #pragma unroll
  for (int s = 1; s < KSPLIT; ++s) {
    float4 b = *(const float4*)&P[(size_t)s * (M_TOT * 128) + i];
    a.x += b.x; a.y += b.y; a.z += b.z; a.w += b.w;
  }
  a.x = tanhf(a.x); a.y = tanhf(a.y); a.z = tanhf(a.z); a.w = tanhf(a.w);
  *(float4*)&X[i] = a;
}

// ---------------------------------------------------------------------------
// bn-MFMA (R13, replaces fp32 k_gemm_bn): C[6400,N] = A[6400,K] @ Bw[N,K]^T
// + bias (opt sigmoid*mask). The fp32 version was VALU-bound (~25% util,
// est 55-100us for the trio); this moves it to the idle matrix pipe with
// the PROVEN hi/lo bf16 3-MFMA split. BM=16, 512 threads, grid (400, 3):
// wave w owns nt = blockIdx.y*8 + w (nt padded to 24; Bt zero rows make
// padded tiles inert; col<N store guard). Single A stage + one barrier;
// B prefetched to regs before the stage (KC*2 short8: KC=8 -> 64 VGPR,
// budget OK at 8 waves). Compiler handles all waitcnts (plain loads).
// ---------------------------------------------------------------------------
template<int KC, int ACT>
__global__ __launch_bounds__(512) void k_bn_mfma(
    const float* __restrict__ A, const unsigned short* __restrict__ Bt,
    const float* __restrict__ bias, const float* __restrict__ maskv,
    float* __restrict__ C, int N, int ldc) {
  constexpr int K  = KC * 32;
  constexpr int PL = KC * 24 * 512;     // ushorts per Bt plane
  __shared__ __align__(16) unsigned short As2[2][KC * 512];  // hi/lo planes
  const int tid  = threadIdx.x;
  const int lane = tid & 63;
  const int w    = tid >> 6;
  const int mrow = blockIdx.x * 16;
  const int nt   = blockIdx.y * 8 + w;

  // B fragments (register-resident, loaded once)
  short8 bh[KC], bl[KC];
  #pragma unroll
  for (int kc = 0; kc < KC; ++kc) {
    const size_t o = ((size_t)(kc * 24 + nt) * 64 + lane) * 8;
    bh[kc] = *(const short8*)&Bt[o];
    bl[kc] = *(const short8*)&Bt[(size_t)PL + o];
  }

  // A stage: row am = tid>>5, quad q0 = tid&31 (+32 for K=256's 2nd half).
  const int am = tid >> 5;
  const int q0 = tid & 31;
  constexpr int NQ = K / 128;           // float4 loads per thread (1 or 2)
  float4 av[NQ];
  #pragma unroll
  for (int i = 0; i < NQ; ++i)
    av[i] = *(const float4*)&A[(size_t)(mrow + am) * K + (q0 + 32 * i) * 4];
  #pragma unroll
  for (int i = 0; i < NQ; ++i) {
    const int q = q0 + 32 * i;
    const int base = (am + 16 * (q >> 1)) * 8 + (q & 1) * 4;
    float v[4] = {av[i].x, av[i].y, av[i].z, av[i].w};
    short4v h4, l4;
    #pragma unroll
    for (int j = 0; j < 4; ++j) {
      unsigned short hb = f32_to_bf16_rne(v[j]);
      unsigned short lb = f32_to_bf16_rne(v[j] - bf16_bits_to_f32(hb));
      h4[j] = (short)hb;
      l4[j] = (short)lb;
    }
    *(short4v*)&As2[0][base] = h4;
    *(short4v*)&As2[1][base] = l4;
  }
  __syncthreads();

  f32x4 acc;
  #pragma unroll
  for (int q = 0; q < 4; ++q) acc[q] = 0.0f;
  #pragma unroll
  for (int kc = 0; kc < KC; ++kc) {
    const int slot = (lane & 15) + 64 * kc + 16 * (lane >> 4);
    short8 a_hi = *(const short8*)&As2[0][slot * 8];
    short8 a_lo = *(const short8*)&As2[1][slot * 8];
    acc = __builtin_amdgcn_mfma_f32_16x16x32_bf16(a_hi, bl[kc], acc, 0, 0, 0);
    acc = __builtin_amdgcn_mfma_f32_16x16x32_bf16(a_lo, bh[kc], acc, 0, 0, 0);
    acc = __builtin_amdgcn_mfma_f32_16x16x32_bf16(a_hi, bh[kc], acc, 0, 0, 0);
  }

  // epilogue: col = nt*16 + (lane&15), row = mrow + (lane>>4)*4 + r
  const int col = nt * 16 + (lane & 15);
  if (col < N) {
    const float bv = bias[col];
    #pragma unroll
    for (int r = 0; r < 4; ++r) {
      const int m = mrow + ((lane >> 4) << 2) + r;
      float v = acc[r] + bv;
      if (ACT) v = sigmoidf_(v) * maskv[m];
      C[(size_t)m * ldc + col] = v;
    }
  }
}

// ---------------------------------------------------------------------------
// GRU scan v3 (R5-proven; R11 taught: waves/block x regs/thread <= 2048).
// One block per batch row; 512 threads. Weights pre-rotated at load.
// n-gate bias INSIDE r*: n = tanh(xn + r*(Wn.h + bn)).
// ---------------------------------------------------------------------------
__global__ __launch_bounds__(512) void k_gru(
    const float* __restrict__ xW, const float* __restrict__ Whh,
    const float* __restrict__ bhh, float* __restrict__ Hout) {
  const int b = blockIdx.x;
  const int tid = threadIdx.x;
  const int j  = tid >> 2;
  const int qf = tid & 3;
  __shared__ __align__(16) float hs[2][128];

  float4 wr[8], wz[8], wn[8];
  {
    const float* pr = Whh + (size_t)j * 128 + qf * 32;
    const float* pz = Whh + (size_t)(j + 128) * 128 + qf * 32;
    const float* pn = Whh + (size_t)(j + 256) * 128 + qf * 32;
    #pragma unroll
    for (int k = 0; k < 8; ++k) {
      const int c = (k + qf * 2) & 7;   // rotation folded into the LOAD
      wr[k] = *(const float4*)(pr + c * 4);
      wz[k] = *(const float4*)(pz + c * 4);
      wn[k] = *(const float4*)(pn + c * 4);
    }
  }
  const float br = bhh[j], bz = bhh[j + 128], bn_ = bhh[j + 256];

  if (tid < 128) hs[0][tid] = 0.0f;
  const float* xwb = xW + (size_t)b * 50 * 384;
  float xr = 0.f, xz = 0.f, xn = 0.f;
  if (qf == 0) { xr = xwb[j]; xz = xwb[128 + j]; xn = xwb[256 + j]; }
  __syncthreads();

  int cur = 0;
  for (int t = 0; t < 50; ++t) {
    float nxr = 0.f, nxz = 0.f, nxn = 0.f;
    if (qf == 0 && t + 1 < 50) {
      const float* xwn = xwb + (size_t)(t + 1) * 384;
      nxr = xwn[j]; nxz = xwn[128 + j]; nxn = xwn[256 + j];
    }

    float ar = 0.f, az = 0.f, an = 0.f;
    #pragma unroll
    for (int k = 0; k < 8; ++k) {
      const int c = (k + qf * 2) & 7;   // runtime -> LDS address only
      float4 hv = *(const float4*)&hs[cur][qf * 32 + c * 4];
      ar += wr[k].x * hv.x + wr[k].y * hv.y + wr[k].z * hv.z + wr[k].w * hv.w;
      az += wz[k].x * hv.x + wz[k].y * hv.y + wz[k].z * hv.z + wz[k].w * hv.w;
      an += wn[k].x * hv.x + wn[k].y * hv.y + wn[k].z * hv.z + wn[k].w * hv.w;
    }
    ar += __shfl_xor(ar, 1); ar += __shfl_xor(ar, 2);
    az += __shfl_xor(az, 1); az += __shfl_xor(az, 2);
    an += __shfl_xor(an, 1); an += __shfl_xor(an, 2);

    if (qf == 0) {
      float r = sigmoidf_(xr + ar + br);
      float z = sigmoidf_(xz + az + bz);
      float nn = tanhf(xn + r * (an + bn_));   // bias INSIDE r*
      float h = (1.f - z) * nn + z * hs[cur][j];
      hs[cur ^ 1][j] = h;
      Hout[(size_t)(b * 50 + t) * 128 + j] = h;
    }
    __syncthreads();
    cur ^= 1;
    xr = nxr; xz = nxz; xn = nxn;
  }
}

// ---------------------------------------------------------------------------
// Attention: per (b,t) block (6400 blocks, 128 threads).
// ---------------------------------------------------------------------------
__global__ __launch_bounds__(128) void k_attn(
    const float* __restrict__ H2, const int* __restrict__ F,
    const float* __restrict__ emb, float* __restrict__ S) {
  const int m = blockIdx.x;
  const int tid = threadIdx.x;
  __shared__ __align__(16) float outs[128];
  __shared__ __align__(16) float Ls[64][132];
  __shared__ float hls[64];
  __shared__ float wts[64];
  __shared__ int fs[64];

  outs[tid] = H2[(size_t)m * 128 + tid];
  if (tid < 64) fs[tid] = F[(size_t)m * 64 + tid];
  __syncthreads();

  #pragma unroll
  for (int i = 0; i < 16; ++i) {
    int idx = tid + i * 128;
    int a = idx >> 5, c4 = idx & 31;
    float4 v = *(const float4*)&emb[(size_t)fs[a] * 128 + c4 * 4];
    *(float4*)&Ls[a][c4 * 4] = v;
  }
  __syncthreads();

  {
    const int a = tid >> 1, hf = tid & 1;
    float sum = 0.f;
    #pragma unroll
    for (int j = 0; j < 16; ++j) {
      float4 lv = *(const float4*)&Ls[a][hf * 64 + j * 4];
      float4 ov = *(const float4*)&outs[hf * 64 + j * 4];
      sum += lv.x * ov.x + lv.y * ov.y + lv.z * ov.z + lv.w * ov.w;
    }
    float other = __shfl_xor(sum, 1);
    sum += other;
    if (hf == 0) hls[a] = sum + (fs[a] > 0 ? 0.0f : -1e30f);
  }
  __syncthreads();

  if (tid < 64) {
    float v = hls[tid];
    float mx = v;
    #pragma unroll
    for (int o = 32; o; o >>= 1) mx = fmaxf(mx, __shfl_xor(mx, o));
    float e = __expf(v - mx);
    float sm = e;
    #pragma unroll
    for (int o = 32; o; o >>= 1) sm += __shfl_xor(sm, o);
    wts[tid] = e / sm;
  }
  __syncthreads();

  float kv = 0.f;
  #pragma unroll 8
  for (int a2 = 0; a2 < 64; ++a2) kv += wts[a2] * Ls[a2][tid];

  S[(size_t)m * 256 + tid] = outs[tid];
  S[(size_t)m * 256 + 128 + tid] = kv;
}

// ---------------------------------------------------------------------------
extern "C" void kernel_launch(void* const* d_in, const int* in_sizes, int n_in,
                              void* d_out, int out_size, void* d_ws, size_t ws_size,
                              hipStream_t stream) {
  const float* inputs_x  = (const float*)d_in[0];
  const int*   inputs_f  = (const int*)d_in[1];
  const float* mask_seqs = (const float*)d_in[2];
  const float* dag_emb   = (const float*)d_in[3];
  const float* embed_a   = (const float*)d_in[4];
  const float* Wih0 = (const float*)d_in[5];
  const float* Whh0 = (const float*)d_in[6];
  const float* bih0 = (const float*)d_in[7];
  const float* bhh0 = (const float*)d_in[8];
  const float* Wih1 = (const float*)d_in[9];
  const float* Whh1 = (const float*)d_in[10];
  const float* bih1 = (const float*)d_in[11];
  const float* bhh1 = (const float*)d_in[12];
  const float* fc_w = (const float*)d_in[13];
  const float* fc_b = (const float*)d_in[14];
  float* out = (float*)d_out;

  float* ws = (float*)d_ws;
  // P: KSPLIT(=10) slots of 819200; X aliases P0; S aliases P1-2 (P dead
  // after reduce). xW/H1/H2 follow; Wt (2.5MB) aliases H1 (dead before gru
  // writes H1; H2 starts 3.28MB after H1 -- beyond Wt). Bt0/1/2 (786KB of
  // bn-MFMA weights) sit AFTER H2: written once by prep, read-only after.
  // Total ~50MB << ws (fill shows 488MB).
  float* P  = ws;
  float* X  = P;                       // aliases P slot 0 (reduce in-place safe)
  float* S  = P + 819200;              // aliases P slots 1-2 (P dead after reduce)
  float* xW = ws + KSPLIT * 819200;
  float* H1 = xW + 2457600;
  float* H2 = H1 + 819200;
  unsigned short* Wt  = (unsigned short*)H1;
  unsigned short* Bt0 = (unsigned short*)(H2 + 819200);   // 2*49152 ushorts
  unsigned short* Bt1 = Bt0 + 2 * 49152;                  // 2*49152
  unsigned short* Bt2 = Bt1 + 2 * 49152;                  // 2*98304

  k_prep<<<402, 256, 0, stream>>>(dag_emb, Wih0, Wih1, fc_w, Wt, Bt0, Bt1, Bt2);
  k_gemm_mfma<<<dim3(50, KSPLIT), 512, 0, stream>>>(inputs_x, Wt, P);
  k_reduce_tanh<<<800, 256, 0, stream>>>(P, X);
  k_bn_mfma<4, 0><<<dim3(400, 3), 512, 0, stream>>>(X, Bt0, bih0, nullptr, xW, 384, 384);
  k_gru<<<128, 512, 0, stream>>>(xW, Whh0, bhh0, H1);
  k_bn_mfma<4, 0><<<dim3(400, 3), 512, 0, stream>>>(H1, Bt1, bih1, nullptr, xW, 384, 384);
  k_gru<<<128, 512, 0, stream>>>(xW, Whh1, bhh1, H2);
  k_attn<<<6400, 128, 0, stream>>>(H2, inputs_f, embed_a, S);
  k_bn_mfma<8, 1><<<dim3(400, 3), 512, 0, stream>>>(S, Bt2, fc_b, mask_seqs, out, NC, NC);
}

// Round 8
// 369.280 us; speedup vs baseline: 3.5479x; 1.0059x over previous
//
#include <hip/hip_runtime.h>
#include <math.h>

#define B_DIM 128
#define T_DIM 50
#define LEAF  4880
#define A_DIM 64
#define ATTN  128
#define RNN   128
#define NC    283
#define M_TOT (B_DIM*T_DIM)   // 6400
#define KSPLIT 10
#define NCH 153               // ceil(4880/32); chunk 152 has 16 valid k
#define WT_PLANE (NCH*512*8)  // 626688 ushort per plane (hi / lo)

using short8 = __attribute__((ext_vector_type(8))) short;
using short4v = __attribute__((ext_vector_type(4))) short;
using f32x4  = __attribute__((ext_vector_type(4))) float;

__device__ __forceinline__ float sigmoidf_(float x) {
  return 1.0f / (1.0f + __expf(-x));
}
// Fast tanh for the GRU's serial critical path: 1 exp + native rcp
// (vs branchy libm tanhf). |err| ~1e-6; compounded over 50 steps ~5e-5,
// far under the 0.0039 absmax scale. Clamp avoids inf/inf at |x|>15.
__device__ __forceinline__ float tanhf_fast(float x) {
  x = fminf(fmaxf(x, -15.f), 15.f);
  float e = __expf(2.f * x);
  return (e - 1.f) * __builtin_amdgcn_rcpf(e + 1.f);
}

// RNE fp32 -> bf16 bits
__device__ __forceinline__ unsigned short f32_to_bf16_rne(float f) {
  unsigned int u = __float_as_uint(f);
  unsigned int r = u + 0x7FFFu + ((u >> 16) & 1u);
  return (unsigned short)(r >> 16);
}
__device__ __forceinline__ float bf16_bits_to_f32(unsigned short b) {
  return __uint_as_float(((unsigned int)b) << 16);
}

// ---------------------------------------------------------------------------
// Unified prep: (a) W[4880,128] -> Wt MFMA B-fragment order (hi/lo planes),
// (b) Wih0/Wih1/fc_w -> Bt0/Bt1/Bt2 fragment order for bn-MFMA (nt padded
// to 24; n >= N rows zeroed so padded tiles are inert).
// ---------------------------------------------------------------------------
__global__ __launch_bounds__(256) void k_prep(
    const float* __restrict__ Wd,
    const float* __restrict__ Wih0, const float* __restrict__ Wih1,
    const float* __restrict__ fcw,
    unsigned short* __restrict__ Wt,
    unsigned short* __restrict__ Bt0, unsigned short* __restrict__ Bt1,
    unsigned short* __restrict__ Bt2) {
  const int bx = blockIdx.x;
  const int tid = threadIdx.x;
  if (bx < 306) {
    const int u = bx * 256 + tid;   // 0 .. 78335 (NCH*512)
    const int c = u >> 9, rem = u & 511;
    const int nt = rem >> 6, lane = rem & 63;
    const int n = nt * 16 + (lane & 15);
    const int kb = c * 32 + ((lane >> 4) << 3);
    short8 h8, l8;
    #pragma unroll
    for (int j = 0; j < 8; ++j) {
      int k = kb + j;
      float v = (k < LEAF) ? Wd[(size_t)k * 128 + n] : 0.0f;
      unsigned short hb = f32_to_bf16_rne(v);
      unsigned short lb = f32_to_bf16_rne(v - bf16_bits_to_f32(hb));
      h8[j] = (short)hb;
      l8[j] = (short)lb;
    }
    *(short8*)&Wt[(size_t)u * 8] = h8;
    *(short8*)&Wt[(size_t)WT_PLANE + (size_t)u * 8] = l8;
  } else {
    const float* src; unsigned short* dst; int N, K, s0;
    if (bx < 330)      { src = Wih0; dst = Bt0; N = 384; K = 128; s0 = (bx - 306) * 256; }
    else if (bx < 354) { src = Wih1; dst = Bt1; N = 384; K = 128; s0 = (bx - 330) * 256; }
    else               { src = fcw;  dst = Bt2; N = NC;  K = 256; s0 = (bx - 354) * 256; }
    const int s = s0 + tid;
    const int PL = (K / 32) * 24 * 512;
    const int kc = s / (24 * 64);
    const int r  = s % (24 * 64);
    const int nt = r >> 6, lane = r & 63;
    const int n  = nt * 16 + (lane & 15);
    const int kb = kc * 32 + ((lane >> 4) << 3);
    short8 h8, l8;
    #pragma unroll
    for (int j = 0; j < 8; ++j) {
      float v = (n < N) ? src[(size_t)n * K + kb + j] : 0.0f;
      unsigned short hb = f32_to_bf16_rne(v);
      unsigned short lb = f32_to_bf16_rne(v - bf16_bits_to_f32(hb));
      h8[j] = (short)hb;
      l8[j] = (short)lb;
    }
    *(short8*)&dst[(size_t)s * 8] = h8;
    *(short8*)&dst[(size_t)PL + (size_t)s * 8] = l8;
  }
}

// ---------------------------------------------------------------------------
// Big GEMM via MFMA, v8: BM=64 @ KSPLIT=10 -> 1000 blocks, 4 blocks/CU.
// R13 accounting: v7 (BM=128, 2 blocks/CU) per chunk-period had ~1750cyc of
// accounted work vs ~4300 wall -> stall-bound with half the wave slots idle.
// v8 doubles resident waves (32/CU, launch_bounds(512,8), 16KB LDS dbuf) at
// IDENTICAL total traffic (wave-chunks 2x but concurrency 2x). Predict
// gemm 55 -> ~42-48us. Body = proven v6: A staged 1 float4/thread
// (8 threads/row), vmcnt entry set [B(c)x2, A(c+1)], waits 3/2/0.
// Arithmetic: 3-MFMA hi/lo -> absmax bit-identical.
// ---------------------------------------------------------------------------
__global__ __launch_bounds__(512, 8) void k_gemm_mfma(
    const float* __restrict__ Ax, const unsigned short* __restrict__ Wt,
    float* __restrict__ P) {
  __shared__ __align__(16) unsigned short As[2][4096];  // 16 KB [buf][plane*2048 + frag]
  const int tid  = threadIdx.x;
  const int lane = tid & 63;
  const int w    = tid >> 6;     // wave id = nt tile (16 cols each)
  const int M0   = blockIdx.x * 64;
  const int s    = blockIdx.y;
  const int c0   = (s * NCH) / KSPLIT;
  const int c1   = ((s + 1) * NCH) / KSPLIT;

  // A staging map: row am = tid>>3, k-quad kq = tid&7 (8 threads/row, 128B).
  const int am = tid >> 3;
  const int kq = tid & 7;
  const float* pA = Ax + (size_t)(M0 + am) * LEAF;
  // elem A[row][k] at (row>>4)*512 + ((row&15) + 16*(k>>3))*8 + (k&7)
  const int a_idx = (am >> 4) * 512 + ((am & 15) + 16 * (kq >> 1)) * 8 + (kq & 1) * 4;

  f32x4 acc[4];
  #pragma unroll
  for (int i = 0; i < 4; ++i) {
    #pragma unroll
    for (int q = 0; q < 4; ++q) acc[i][q] = 0.0f;
  }

  float4 rA_a, rA_b;                 // ping-pong A prefetch (depth 2)
  short8 bh_a, bl_a, bh_b, bl_b;     // ping-pong B fragments (depth 1)

  auto issueB = [&](int c, short8& bh, short8& bl) {
    const size_t o = ((size_t)c * 512 + w * 64 + lane) * 8;
    bh = *(const short8*)&Wt[o];
    bl = *(const short8*)&Wt[(size_t)WT_PLANE + o];
  };
  auto issueA = [&](int c, float4& ra) {
    int kk = c * 32 + kq * 4;
    kk = min(kk, LEAF - 4);            // clamp (no skip): uniform vmcnt counts;
    ra = *(const float4*)(pA + kk);    // clamped dup data x Wt zero rows = 0
  };
  auto storeA = [&](int p, float4 ra) {
    float v[4] = {ra.x, ra.y, ra.z, ra.w};
    short4v h4, l4;
    #pragma unroll
    for (int j = 0; j < 4; ++j) {
      unsigned short hb = f32_to_bf16_rne(v[j]);
      unsigned short lb = f32_to_bf16_rne(v[j] - bf16_bits_to_f32(hb));
      h4[j] = (short)hb;
      l4[j] = (short)lb;
    }
    *(short4v*)&As[p][a_idx] = h4;
    *(short4v*)&As[p][2048 + a_idx] = l4;
  };
  auto compute = [&](int p, const short8& bh, const short8& bl) {
    #pragma unroll
    for (int m = 0; m < 4; ++m) {
      short8 a_hi = *(const short8*)&As[p][m * 512 + lane * 8];
      short8 a_lo = *(const short8*)&As[p][2048 + m * 512 + lane * 8];
      acc[m] = __builtin_amdgcn_mfma_f32_16x16x32_bf16(a_hi, bl, acc[m], 0, 0, 0);
      acc[m] = __builtin_amdgcn_mfma_f32_16x16x32_bf16(a_lo, bh, acc[m], 0, 0, 0);
      acc[m] = __builtin_amdgcn_mfma_f32_16x16x32_bf16(a_hi, bh, acc[m], 0, 0, 0);
    }
  };

  // ---- prologue ----
  {
    float4 ta;
    issueA(c0, ta);
    asm volatile("s_waitcnt vmcnt(0)" ::: "memory");
    storeA(0, ta);
    issueB(c0, bh_a, bl_a);                      // 2 loads
    asm volatile("" ::: "memory");
    if (c0 + 1 < c1) issueA(c0 + 1, rA_a);       // 1 load
    asm volatile("s_waitcnt lgkmcnt(0)" ::: "memory");
    __builtin_amdgcn_s_barrier();
    asm volatile("" ::: "memory");
    // outstanding entering loop: [B(c0) x2, A(c0+1)]
  }

#define GEMM_ITER(BHc, BLc, BHn, BLn, RAc, RAn)                               \
  {                                                                           \
    const int p = (c - c0) & 1;                                               \
    const bool has1 = (c + 1 < c1), has2 = (c + 2 < c1);                      \
    if (has1) { issueB(c + 1, BHn, BLn); asm volatile("" ::: "memory"); }     \
    if (has2) { issueA(c + 2, RAn);      asm volatile("" ::: "memory"); }     \
    if (has1) {                                                               \
      if (has2) { asm volatile("s_waitcnt vmcnt(3)" ::: "memory"); }          \
      else      { asm volatile("s_waitcnt vmcnt(2)" ::: "memory"); }          \
    } else      { asm volatile("s_waitcnt vmcnt(0)" ::: "memory"); }          \
    compute(p, BHc, BLc);                                                     \
    if (has1) storeA(p ^ 1, RAc);                                             \
    asm volatile("s_waitcnt lgkmcnt(0)" ::: "memory");                        \
    __builtin_amdgcn_s_barrier();                                             \
    asm volatile("" ::: "memory");                                            \
    ++c;                                                                      \
  }

  int c = c0;
  while (c < c1) {
    GEMM_ITER(bh_a, bl_a, bh_b, bl_b, rA_a, rA_b);
    if (c < c1) GEMM_ITER(bh_b, bl_b, bh_a, bl_a, rA_b, rA_a);
  }
#undef GEMM_ITER

  // epilogue: C/D layout col=lane&15, row=(lane>>4)*4+r ; cols = w*16..w*16+15
  float* outp = P + (size_t)s * ((size_t)M_TOT * 128);
  const int col0 = w * 16 + (lane & 15);
  #pragma unroll
  for (int m = 0; m < 4; ++m) {
    const int rbase = M0 + m * 16 + ((lane >> 4) << 2);
    #pragma unroll
    for (int r = 0; r < 4; ++r)
      outp[(size_t)(rbase + r) * 128 + col0] = acc[m][r];
  }
}

// ---------------------------------------------------------------------------
// Reduce KSPLIT partials + tanh (X aliases P slot 0; elementwise-safe).
// ---------------------------------------------------------------------------
__global__ __launch_bounds__(256) void k_reduce_tanh(
    float* __restrict__ P, float* __restrict__ X) {
  const size_t i = ((size_t)blockIdx.x * 256 + threadIdx.x) * 4;
  float4 a = *(const float4*)&P[i];
  #pragma unroll
  for (int s = 1; s < KSPLIT; ++s) {
    float4 b = *(const float4*)&P[(size_t)s * (M_TOT * 128) + i];
    a.x += b.x; a.y += b.y; a.z += b.z; a.w += b.w;
  }
  a.x = tanhf(a.x); a.y = tanhf(a.y); a.z = tanhf(a.z); a.w = tanhf(a.w);
  *(float4*)&X[i] = a;
}

// ---------------------------------------------------------------------------
// bn-MFMA (R13-proven, -121us vs fp32 trio): C = A @ Bw^T + bias
// (opt sigmoid*mask). BM=16, 512 threads, grid (400,3); B fragments
// register-resident; single A stage + one barrier; col<N store guard.
// ---------------------------------------------------------------------------
template<int KC, int ACT>
__global__ __launch_bounds__(512) void k_bn_mfma(
    const float* __restrict__ A, const unsigned short* __restrict__ Bt,
    const float* __restrict__ bias, const float* __restrict__ maskv,
    float* __restrict__ C, int N, int ldc) {
  constexpr int K  = KC * 32;
  constexpr int PL = KC * 24 * 512;     // ushorts per Bt plane
  __shared__ __align__(16) unsigned short As2[2][KC * 512];  // hi/lo planes
  const int tid  = threadIdx.x;
  const int lane = tid & 63;
  const int w    = tid >> 6;
  const int mrow = blockIdx.x * 16;
  const int nt   = blockIdx.y * 8 + w;

  short8 bh[KC], bl[KC];
  #pragma unroll
  for (int kc = 0; kc < KC; ++kc) {
    const size_t o = ((size_t)(kc * 24 + nt) * 64 + lane) * 8;
    bh[kc] = *(const short8*)&Bt[o];
    bl[kc] = *(const short8*)&Bt[(size_t)PL + o];
  }

  const int am = tid >> 5;
  const int q0 = tid & 31;
  constexpr int NQ = K / 128;           // float4 loads per thread (1 or 2)
  float4 av[NQ];
  #pragma unroll
  for (int i = 0; i < NQ; ++i)
    av[i] = *(const float4*)&A[(size_t)(mrow + am) * K + (q0 + 32 * i) * 4];
  #pragma unroll
  for (int i = 0; i < NQ; ++i) {
    const int q = q0 + 32 * i;
    const int base = (am + 16 * (q >> 1)) * 8 + (q & 1) * 4;
    float v[4] = {av[i].x, av[i].y, av[i].z, av[i].w};
    short4v h4, l4;
    #pragma unroll
    for (int j = 0; j < 4; ++j) {
      unsigned short hb = f32_to_bf16_rne(v[j]);
      unsigned short lb = f32_to_bf16_rne(v[j] - bf16_bits_to_f32(hb));
      h4[j] = (short)hb;
      l4[j] = (short)lb;
    }
    *(short4v*)&As2[0][base] = h4;
    *(short4v*)&As2[1][base] = l4;
  }
  __syncthreads();

  f32x4 acc;
  #pragma unroll
  for (int q = 0; q < 4; ++q) acc[q] = 0.0f;
  #pragma unroll
  for (int kc = 0; kc < KC; ++kc) {
    const int slot = (lane & 15) + 64 * kc + 16 * (lane >> 4);
    short8 a_hi = *(const short8*)&As2[0][slot * 8];
    short8 a_lo = *(const short8*)&As2[1][slot * 8];
    acc = __builtin_amdgcn_mfma_f32_16x16x32_bf16(a_hi, bl[kc], acc, 0, 0, 0);
    acc = __builtin_amdgcn_mfma_f32_16x16x32_bf16(a_lo, bh[kc], acc, 0, 0, 0);
    acc = __builtin_amdgcn_mfma_f32_16x16x32_bf16(a_hi, bh[kc], acc, 0, 0, 0);
  }

  const int col = nt * 16 + (lane & 15);
  if (col < N) {
    const float bv = bias[col];
    #pragma unroll
    for (int r = 0; r < 4; ++r) {
      const int m = mrow + ((lane >> 4) << 2) + r;
      float v = acc[r] + bv;
      if (ACT) v = sigmoidf_(v) * maskv[m];
      C[(size_t)m * ldc + col] = v;
    }
  }
}

// ---------------------------------------------------------------------------
// GRU scan v3.1 (R5-proven structure; R14: fast tanh on the 50-step serial
// path). One block per batch row; 512 threads. Weights pre-rotated at load.
// n-gate bias INSIDE r*: n = tanh(xn + r*(Wn.h + bn)).
// R11 lesson retained: waves/block x regs/thread <= 2048.
// ---------------------------------------------------------------------------
__global__ __launch_bounds__(512) void k_gru(
    const float* __restrict__ xW, const float* __restrict__ Whh,
    const float* __restrict__ bhh, float* __restrict__ Hout) {
  const int b = blockIdx.x;
  const int tid = threadIdx.x;
  const int j  = tid >> 2;
  const int qf = tid & 3;
  __shared__ __align__(16) float hs[2][128];

  float4 wr[8], wz[8], wn[8];
  {
    const float* pr = Whh + (size_t)j * 128 + qf * 32;
    const float* pz = Whh + (size_t)(j + 128) * 128 + qf * 32;
    const float* pn = Whh + (size_t)(j + 256) * 128 + qf * 32;
    #pragma unroll
    for (int k = 0; k < 8; ++k) {
      const int c = (k + qf * 2) & 7;   // rotation folded into the LOAD
      wr[k] = *(const float4*)(pr + c * 4);
      wz[k] = *(const float4*)(pz + c * 4);
      wn[k] = *(const float4*)(pn + c * 4);
    }
  }
  const float br = bhh[j], bz = bhh[j + 128], bn_ = bhh[j + 256];

  if (tid < 128) hs[0][tid] = 0.0f;
  const float* xwb = xW + (size_t)b * 50 * 384;
  float xr = 0.f, xz = 0.f, xn = 0.f;
  if (qf == 0) { xr = xwb[j]; xz = xwb[128 + j]; xn = xwb[256 + j]; }
  __syncthreads();

  int cur = 0;
  for (int t = 0; t < 50; ++t) {
    float nxr = 0.f, nxz = 0.f, nxn = 0.f;
    if (qf == 0 && t + 1 < 50) {
      const float* xwn = xwb + (size_t)(t + 1) * 384;
      nxr = xwn[j]; nxz = xwn[128 + j]; nxn = xwn[256 + j];
    }

    float ar = 0.f, az = 0.f, an = 0.f;
    #pragma unroll
    for (int k = 0; k < 8; ++k) {
      const int c = (k + qf * 2) & 7;   // runtime -> LDS address only
      float4 hv = *(const float4*)&hs[cur][qf * 32 + c * 4];
      ar += wr[k].x * hv.x + wr[k].y * hv.y + wr[k].z * hv.z + wr[k].w * hv.w;
      az += wz[k].x * hv.x + wz[k].y * hv.y + wz[k].z * hv.z + wz[k].w * hv.w;
      an += wn[k].x * hv.x + wn[k].y * hv.y + wn[k].z * hv.z + wn[k].w * hv.w;
    }
    ar += __shfl_xor(ar, 1); ar += __shfl_xor(ar, 2);
    az += __shfl_xor(az, 1); az += __shfl_xor(az, 2);
    an += __shfl_xor(an, 1); an += __shfl_xor(an, 2);

    if (qf == 0) {
      float r = sigmoidf_(xr + ar + br);
      float z = sigmoidf_(xz + az + bz);
      float nn = tanhf_fast(xn + r * (an + bn_));   // bias INSIDE r*
      float h = (1.f - z) * nn + z * hs[cur][j];
      hs[cur ^ 1][j] = h;
      Hout[(size_t)(b * 50 + t) * 128 + j] = h;
    }
    __syncthreads();
    cur ^= 1;
    xr = nxr; xz = nxz; xn = nxn;
  }
}

// ---------------------------------------------------------------------------
// Attention: per (b,t) block (6400 blocks, 128 threads).
// ---------------------------------------------------------------------------
__global__ __launch_bounds__(128) void k_attn(
    const float* __restrict__ H2, const int* __restrict__ F,
    const float* __restrict__ emb, float* __restrict__ S) {
  const int m = blockIdx.x;
  const int tid = threadIdx.x;
  __shared__ __align__(16) float outs[128];
  __shared__ __align__(16) float Ls[64][132];
  __shared__ float hls[64];
  __shared__ float wts[64];
  __shared__ int fs[64];

  outs[tid] = H2[(size_t)m * 128 + tid];
  if (tid < 64) fs[tid] = F[(size_t)m * 64 + tid];
  __syncthreads();

  #pragma unroll
  for (int i = 0; i < 16; ++i) {
    int idx = tid + i * 128;
    int a = idx >> 5, c4 = idx & 31;
    float4 v = *(const float4*)&emb[(size_t)fs[a] * 128 + c4 * 4];
    *(float4*)&Ls[a][c4 * 4] = v;
  }
  __syncthreads();

  {
    const int a = tid >> 1, hf = tid & 1;
    float sum = 0.f;
    #pragma unroll
    for (int j = 0; j < 16; ++j) {
      float4 lv = *(const float4*)&Ls[a][hf * 64 + j * 4];
      float4 ov = *(const float4*)&outs[hf * 64 + j * 4];
      sum += lv.x * ov.x + lv.y * ov.y + lv.z * ov.z + lv.w * ov.w;
    }
    float other = __shfl_xor(sum, 1);
    sum += other;
    if (hf == 0) hls[a] = sum + (fs[a] > 0 ? 0.0f : -1e30f);
  }
  __syncthreads();

  if (tid < 64) {
    float v = hls[tid];
    float mx = v;
    #pragma unroll
    for (int o = 32; o; o >>= 1) mx = fmaxf(mx, __shfl_xor(mx, o));
    float e = __expf(v - mx);
    float sm = e;
    #pragma unroll
    for (int o = 32; o; o >>= 1) sm += __shfl_xor(sm, o);
    wts[tid] = e / sm;
  }
  __syncthreads();

  float kv = 0.f;
  #pragma unroll 8
  for (int a2 = 0; a2 < 64; ++a2) kv += wts[a2] * Ls[a2][tid];

  S[(size_t)m * 256 + tid] = outs[tid];
  S[(size_t)m * 256 + 128 + tid] = kv;
}

// ---------------------------------------------------------------------------
extern "C" void kernel_launch(void* const* d_in, const int* in_sizes, int n_in,
                              void* d_out, int out_size, void* d_ws, size_t ws_size,
                              hipStream_t stream) {
  const float* inputs_x  = (const float*)d_in[0];
  const int*   inputs_f  = (const int*)d_in[1];
  const float* mask_seqs = (const float*)d_in[2];
  const float* dag_emb   = (const float*)d_in[3];
  const float* embed_a   = (const float*)d_in[4];
  const float* Wih0 = (const float*)d_in[5];
  const float* Whh0 = (const float*)d_in[6];
  const float* bih0 = (const float*)d_in[7];
  const float* bhh0 = (const float*)d_in[8];
  const float* Wih1 = (const float*)d_in[9];
  const float* Whh1 = (const float*)d_in[10];
  const float* bih1 = (const float*)d_in[11];
  const float* bhh1 = (const float*)d_in[12];
  const float* fc_w = (const float*)d_in[13];
  const float* fc_b = (const float*)d_in[14];
  float* out = (float*)d_out;

  float* ws = (float*)d_ws;
  // P: KSPLIT(=10) slots of 819200; X aliases P0; S aliases P1-2 (P dead
  // after reduce). xW/H1/H2 follow; Wt (2.5MB) aliases H1 (dead before gru
  // writes H1; H2 starts 3.28MB after H1 -- beyond Wt). Bt0/1/2 after H2.
  float* P  = ws;
  float* X  = P;                       // aliases P slot 0 (reduce in-place safe)
  float* S  = P + 819200;              // aliases P slots 1-2 (P dead after reduce)
  float* xW = ws + KSPLIT * 819200;
  float* H1 = xW + 2457600;
  float* H2 = H1 + 819200;
  unsigned short* Wt  = (unsigned short*)H1;
  unsigned short* Bt0 = (unsigned short*)(H2 + 819200);   // 2*49152 ushorts
  unsigned short* Bt1 = Bt0 + 2 * 49152;                  // 2*49152
  unsigned short* Bt2 = Bt1 + 2 * 49152;                  // 2*98304

  k_prep<<<402, 256, 0, stream>>>(dag_emb, Wih0, Wih1, fc_w, Wt, Bt0, Bt1, Bt2);
  k_gemm_mfma<<<dim3(100, KSPLIT), 512, 0, stream>>>(inputs_x, Wt, P);
  k_reduce_tanh<<<800, 256, 0, stream>>>(P, X);
  k_bn_mfma<4, 0><<<dim3(400, 3), 512, 0, stream>>>(X, Bt0, bih0, nullptr, xW, 384, 384);
  k_gru<<<128, 512, 0, stream>>>(xW, Whh0, bhh0, H1);
  k_bn_mfma<4, 0><<<dim3(400, 3), 512, 0, stream>>>(H1, Bt1, bih1, nullptr, xW, 384, 384);
  k_gru<<<128, 512, 0, stream>>>(xW, Whh1, bhh1, H2);
  k_attn<<<6400, 128, 0, stream>>>(H2, inputs_f, embed_a, S);
  k_bn_mfma<8, 1><<<dim3(400, 3), 512, 0, stream>>>(S, Bt2, fc_b, mask_seqs, out, NC, NC);
}